// Round 1
// baseline (632.489 us; speedup 1.0000x reference)
//
#include <hip/hip_runtime.h>

// Problem constants (baked from reference):
//   J_row: 4096 x 4096 f32, J_col: 4096 x 4096 f32
//   out:   [4][4096][4096] f32; group g uses K-slice [g*1024, (g+1)*1024)
//   group 3: cols 3072:3584 scale 1.0, cols 3584:4096 scale 0.5 (folded into B)

typedef unsigned short ushort_t;
typedef __bf16 bf16x8 __attribute__((ext_vector_type(8)));
typedef float floatx4 __attribute__((ext_vector_type(4)));
typedef unsigned short ushortx8 __attribute__((ext_vector_type(8)));

#define PDIM 4096
#define NG 4
#define KG 1024
#define BM 128
#define BN 128
#define BK 32

__device__ __forceinline__ unsigned short f2bf_rne(float f) {
  union { float f; unsigned u; } v; v.f = f;
  unsigned u = v.u;
  unsigned r = u + 0x7FFFu + ((u >> 16) & 1u);
  return (unsigned short)(r >> 16);
}

// fp32 -> bf16 conversion; blockIdx.y==1 (J_col) scales cols >= 3584 by 0.5.
__global__ void convert_bf16(const float* __restrict__ srcA,
                             const float* __restrict__ srcB,
                             ushort_t* __restrict__ dstA,
                             ushort_t* __restrict__ dstB) {
  const float* src;
  ushort_t* dst;
  int scale_start;
  if (blockIdx.y == 0) { src = srcA; dst = dstA; scale_start = PDIM; }
  else                 { src = srcB; dst = dstB; scale_start = 3584; }
  long long idx = (long long)blockIdx.x * blockDim.x + threadIdx.x; // 8 elems/thread
  long long base = idx * 8;
  int col = (int)(base & (PDIM - 1));
  float s = (col >= scale_start) ? 0.5f : 1.0f;
  const float4* p = (const float4*)(src + base);
  float4 x = p[0];
  float4 y = p[1];
  ushortx8 o;
  o[0] = f2bf_rne(x.x * s); o[1] = f2bf_rne(x.y * s);
  o[2] = f2bf_rne(x.z * s); o[3] = f2bf_rne(x.w * s);
  o[4] = f2bf_rne(y.x * s); o[5] = f2bf_rne(y.y * s);
  o[6] = f2bf_rne(y.z * s); o[7] = f2bf_rne(y.w * s);
  *(ushortx8*)(dst + base) = o;
}

__device__ __forceinline__ void async_copy16(const ushort_t* g, ushort_t* l) {
  __builtin_amdgcn_global_load_lds(
      (const __attribute__((address_space(1))) unsigned int*)(g),
      (__attribute__((address_space(3))) unsigned int*)(l),
      16, 0, 0);
}

// C[g][i][j] = sum_k Ab[i][g*1024+k] * Bb[j][g*1024+k]
// m97-style: 128x128 tile, BK=32, 4 waves (2x2), each wave 4x4 frags of 16x16x32.
__global__ __launch_bounds__(256) void gemm_grouped(
    const ushort_t* __restrict__ Ab, const ushort_t* __restrict__ Bb,
    float* __restrict__ out) {
  // LDS: A tile [4][128][8] (k-chunk, row, k%8) then B tile same. 16 KB.
  __shared__ ushort_t lds[2 * 4096];

  const int tid = threadIdx.x;
  const int wave = tid >> 6;
  const int lane = tid & 63;
  const int m16 = lane & 15;
  const int quad = lane >> 4;
  const int wm = wave & 1;
  const int wn = wave >> 1;

  const int row0 = blockIdx.y * BM;
  const int col0 = blockIdx.x * BN;
  const int g = blockIdx.z;
  const int kbase = g * KG;

  // Staging: 16 chunks of 1KB (64 lanes x 16B); 4 chunks per wave.
  // Chunk (q,c): k-chunk q (cols q*8..q*8+7 of BK), rows c*64..c*64+63.
  // XOR-swizzle rows by (q<<1) on the global-read side so that LDS slot
  // (q, m) holds global row m ^ (q<<1)  -> fragment ds_read_b128 spreads banks.
  const ushort_t* gptr[4];
  ushort_t* lptr[4];
#pragma unroll
  for (int s = 0; s < 4; ++s) {
    int ch = wave * 4 + s;
    int isB = ch >> 3;
    int ch2 = ch & 7;
    int q = ch2 >> 1;
    int c = ch2 & 1;
    int grow = (isB ? col0 : row0) + c * 64 + (lane ^ (q << 1));
    const ushort_t* mat = isB ? Bb : Ab;
    gptr[s] = mat + (size_t)grow * PDIM + kbase + q * 8;
    lptr[s] = &lds[isB * 4096 + q * 1024 + c * 512];
  }

  floatx4 acc[4][4];
#pragma unroll
  for (int i = 0; i < 4; ++i)
#pragma unroll
    for (int j = 0; j < 4; ++j)
      acc[i][j] = (floatx4){0.f, 0.f, 0.f, 0.f};

  // Fragment LDS element offsets (A-operand: m=lane&15, k=quad*8+j).
  int a_off[4], b_off[4];
#pragma unroll
  for (int i = 0; i < 4; ++i) {
    a_off[i] = quad * 1024 + (wm * 64 + i * 16 + (m16 ^ (quad << 1))) * 8;
    b_off[i] = 4096 + quad * 1024 + (wn * 64 + i * 16 + (m16 ^ (quad << 1))) * 8;
  }

  for (int kt = 0; kt < KG; kt += BK) {
#pragma unroll
    for (int s = 0; s < 4; ++s)
      async_copy16(gptr[s] + kt, lptr[s]);
    __syncthreads();  // compiler drains vmcnt before s_barrier

    bf16x8 af[4], bfr[4];
#pragma unroll
    for (int i = 0; i < 4; ++i) af[i] = *(const bf16x8*)&lds[a_off[i]];
#pragma unroll
    for (int i = 0; i < 4; ++i) bfr[i] = *(const bf16x8*)&lds[b_off[i]];

#pragma unroll
    for (int mi = 0; mi < 4; ++mi)
#pragma unroll
      for (int ni = 0; ni < 4; ++ni)
        acc[mi][ni] = __builtin_amdgcn_mfma_f32_16x16x32_bf16(
            af[mi], bfr[ni], acc[mi][ni], 0, 0, 0);

    __syncthreads();  // protect LDS from next iteration's staging
  }

  // Epilogue: C/D layout col=lane&15, row=quad*4+reg.
  float* outp = out + (size_t)g * PDIM * PDIM;
  const int orow0 = row0 + wm * 64 + quad * 4;
  const int ocol0 = col0 + wn * 64 + m16;
#pragma unroll
  for (int mi = 0; mi < 4; ++mi)
#pragma unroll
    for (int ni = 0; ni < 4; ++ni)
#pragma unroll
      for (int v = 0; v < 4; ++v)
        outp[(size_t)(orow0 + mi * 16 + v) * PDIM + (ocol0 + ni * 16)] =
            acc[mi][ni][v];
}

extern "C" void kernel_launch(void* const* d_in, const int* in_sizes, int n_in,
                              void* d_out, int out_size, void* d_ws, size_t ws_size,
                              hipStream_t stream) {
  const float* J_row = (const float*)d_in[0];
  const float* J_col = (const float*)d_in[1];
  float* out = (float*)d_out;

  ushort_t* Ab = (ushort_t*)d_ws;                       // 32 MB
  ushort_t* Bb = Ab + (size_t)PDIM * PDIM;              // 32 MB

  dim3 cgrid(PDIM * PDIM / 8 / 256, 2);                 // (8192, 2)
  convert_bf16<<<cgrid, 256, 0, stream>>>(J_row, J_col, Ab, Bb);

  dim3 ggrid(PDIM / BN, PDIM / BM, NG);                 // (32, 32, 4)
  gemm_grouped<<<ggrid, 256, 0, stream>>>(Ab, Bb, out);
}

// Round 2
// 625.714 us; speedup vs baseline: 1.0108x; 1.0108x over previous
//
#include <hip/hip_runtime.h>

// Problem constants (baked from reference):
//   J_row: 4096 x 4096 f32, J_col: 4096 x 4096 f32
//   out:   [4][4096][4096] f32; group g uses K-slice [g*1024, (g+1)*1024)
//   group 3: cols 3072:3584 scale 1.0, cols 3584:4096 scale 0.5 (folded into B)

typedef unsigned short ushort_t;
typedef __bf16 bf16x8 __attribute__((ext_vector_type(8)));
typedef float floatx4 __attribute__((ext_vector_type(4)));
typedef unsigned short ushortx8 __attribute__((ext_vector_type(8)));

#define PDIM 4096
#define NG 4
#define KG 1024
#define BM 128
#define BN 128
#define BK 32

__device__ __forceinline__ unsigned short f2bf_rne(float f) {
  union { float f; unsigned u; } v; v.f = f;
  unsigned u = v.u;
  unsigned r = u + 0x7FFFu + ((u >> 16) & 1u);
  return (unsigned short)(r >> 16);
}

// fp32 -> bf16 conversion; blockIdx.y==1 (J_col) scales cols >= 3584 by 0.5.
__global__ void convert_bf16(const float* __restrict__ srcA,
                             const float* __restrict__ srcB,
                             ushort_t* __restrict__ dstA,
                             ushort_t* __restrict__ dstB) {
  const float* src;
  ushort_t* dst;
  int scale_start;
  if (blockIdx.y == 0) { src = srcA; dst = dstA; scale_start = PDIM; }
  else                 { src = srcB; dst = dstB; scale_start = 3584; }
  long long idx = (long long)blockIdx.x * blockDim.x + threadIdx.x; // 8 elems/thread
  long long base = idx * 8;
  int col = (int)(base & (PDIM - 1));
  float s = (col >= scale_start) ? 0.5f : 1.0f;
  const float4* p = (const float4*)(src + base);
  float4 x = p[0];
  float4 y = p[1];
  ushortx8 o;
  o[0] = f2bf_rne(x.x * s); o[1] = f2bf_rne(x.y * s);
  o[2] = f2bf_rne(x.z * s); o[3] = f2bf_rne(x.w * s);
  o[4] = f2bf_rne(y.x * s); o[5] = f2bf_rne(y.y * s);
  o[6] = f2bf_rne(y.z * s); o[7] = f2bf_rne(y.w * s);
  *(ushortx8*)(dst + base) = o;
}

__device__ __forceinline__ void async_copy16(const ushort_t* g, ushort_t* l) {
  __builtin_amdgcn_global_load_lds(
      (const __attribute__((address_space(1))) unsigned int*)(g),
      (__attribute__((address_space(3))) unsigned int*)(l),
      16, 0, 0);
}

// C[g][i][j] = sum_k Ab[i][g*1024+k] * Bb[j][g*1024+k]
// m97 shape: grid 32x32, 128x128 tile, BK=32, 4 waves (2x2), 4x4 frags each.
// Each block walks K = 0..4096 continuously, flushing the accumulator to
// out[g] every 1024 columns (the 4 group K-slices are contiguous).
__global__ __launch_bounds__(256) void gemm_grouped(
    const ushort_t* __restrict__ Ab, const ushort_t* __restrict__ Bb,
    float* __restrict__ out) {
  // LDS: A tile [4][128][8] (k-chunk, row, k%8) then B tile same. 16 KB.
  __shared__ ushort_t lds[2 * 4096];

  const int tid = threadIdx.x;
  const int wave = tid >> 6;
  const int lane = tid & 63;
  const int m16 = lane & 15;
  const int quad = lane >> 4;
  const int wm = wave & 1;
  const int wn = wave >> 1;

  const int row0 = blockIdx.y * BM;
  const int col0 = blockIdx.x * BN;

  // Staging: 16 chunks of 1KB (64 lanes x 16B); 4 chunks per wave.
  // Chunk (q,c): k-chunk q (cols q*8..q*8+7 of BK), rows c*64..c*64+63.
  // XOR-swizzle rows by (q<<1) on the global-read side so that LDS slot
  // (q, m) holds global row m ^ (q<<1) -> fragment ds_read_b128 spreads banks.
  const ushort_t* gptr[4];
  ushort_t* lptr[4];
#pragma unroll
  for (int s = 0; s < 4; ++s) {
    int ch = wave * 4 + s;
    int isB = ch >> 3;
    int ch2 = ch & 7;
    int q = ch2 >> 1;
    int c = ch2 & 1;
    int grow = (isB ? col0 : row0) + c * 64 + (lane ^ (q << 1));
    const ushort_t* mat = isB ? Bb : Ab;
    gptr[s] = mat + (size_t)grow * PDIM + q * 8;
    lptr[s] = &lds[isB * 4096 + q * 1024 + c * 512];
  }

  // Fragment LDS element offsets (A-operand: m=lane&15, k=quad*8+j).
  int a_off[4], b_off[4];
#pragma unroll
  for (int i = 0; i < 4; ++i) {
    a_off[i] = quad * 1024 + (wm * 64 + i * 16 + (m16 ^ (quad << 1))) * 8;
    b_off[i] = 4096 + quad * 1024 + (wn * 64 + i * 16 + (m16 ^ (quad << 1))) * 8;
  }

  const int orow0 = row0 + wm * 64 + quad * 4;
  const int ocol0 = col0 + wn * 64 + m16;

  for (int g = 0; g < NG; ++g) {
    floatx4 acc[4][4];
#pragma unroll
    for (int i = 0; i < 4; ++i)
#pragma unroll
      for (int j = 0; j < 4; ++j)
        acc[i][j] = (floatx4){0.f, 0.f, 0.f, 0.f};

    const int kb = g * KG;
    for (int kt = 0; kt < KG; kt += BK) {
#pragma unroll
      for (int s = 0; s < 4; ++s)
        async_copy16(gptr[s] + kb + kt, lptr[s]);
      __syncthreads();  // staging complete (vmcnt drained at barrier)

      bf16x8 af[4], bfr[4];
#pragma unroll
      for (int i = 0; i < 4; ++i) af[i] = *(const bf16x8*)&lds[a_off[i]];
#pragma unroll
      for (int i = 0; i < 4; ++i) bfr[i] = *(const bf16x8*)&lds[b_off[i]];

      __syncthreads();  // all waves done reading LDS; next staging may issue
                        // while the MFMAs below execute (regs only)

#pragma unroll
      for (int mi = 0; mi < 4; ++mi)
#pragma unroll
        for (int ni = 0; ni < 4; ++ni)
          acc[mi][ni] = __builtin_amdgcn_mfma_f32_16x16x32_bf16(
              af[mi], bfr[ni], acc[mi][ni], 0, 0, 0);
    }

    // Epilogue for group g: C/D layout col=lane&15, row=quad*4+reg.
    float* outp = out + (size_t)g * PDIM * PDIM;
#pragma unroll
    for (int mi = 0; mi < 4; ++mi)
#pragma unroll
      for (int ni = 0; ni < 4; ++ni)
#pragma unroll
        for (int v = 0; v < 4; ++v)
          outp[(size_t)(orow0 + mi * 16 + v) * PDIM + (ocol0 + ni * 16)] =
              acc[mi][ni][v];
  }
}

extern "C" void kernel_launch(void* const* d_in, const int* in_sizes, int n_in,
                              void* d_out, int out_size, void* d_ws, size_t ws_size,
                              hipStream_t stream) {
  const float* J_row = (const float*)d_in[0];
  const float* J_col = (const float*)d_in[1];
  float* out = (float*)d_out;

  ushort_t* Ab = (ushort_t*)d_ws;                       // 32 MB
  ushort_t* Bb = Ab + (size_t)PDIM * PDIM;              // 32 MB

  dim3 cgrid(PDIM * PDIM / 8 / 256, 2);                 // (8192, 2)
  convert_bf16<<<cgrid, 256, 0, stream>>>(J_row, J_col, Ab, Bb);

  dim3 ggrid(PDIM / BN, PDIM / BM);                     // (32, 32)
  gemm_grouped<<<ggrid, 256, 0, stream>>>(Ab, Bb, out);
}